// Round 12
// baseline (1438.470 us; speedup 1.0000x reference)
//
#include <hip/hip_runtime.h>
#include <cstddef>

typedef __attribute__((ext_vector_type(8))) _Float16 half8;
typedef __attribute__((ext_vector_type(4))) float f32x4;
typedef __attribute__((ext_vector_type(4))) unsigned short us4;

#define TT 16
#define APAD 72                 // shorts per (row,col) slot: 144 B
#define A_TILE (3*34*APAD)      // step-kernel tile: 7344 shorts
#define CHUNK  8192             // shorts per 16KB weight chunk
#define NB     6                // B reg-pipeline slots (xconv/fallback)
#define PF     5                // prefetch distance (< NB)

__device__ __forceinline__ unsigned short f2h(float f) {
    return __builtin_bit_cast(unsigned short, (_Float16)f);
}
__device__ __forceinline__ float h2f(unsigned short u) {
    return (float)__builtin_bit_cast(_Float16, u);
}
__device__ __forceinline__ float hsig(float z) {
    return fminf(fmaxf(0.2f * z + 0.5f, 0.f), 1.f);
}

// Weight pack (fp16): Wc short idx i = (s*4 + kg)*2048 + n*8 + j, s in [0,36)
// s<18 -> Wx chunk sub=s ; s>=18 -> Wh chunk sub=s-18
__global__ __launch_bounds__(256) void prep_kernel(
    const float* __restrict__ Wx, const float* __restrict__ Wh,
    const float* __restrict__ gamma, const float* __restrict__ beta,
    const float* __restrict__ mean, const float* __restrict__ var,
    unsigned short* __restrict__ Wc, float* __restrict__ bn)
{
    if (blockIdx.x == 1152) {
        if (threadIdx.x < 64) {
            const int c = threadIdx.x;
            const float inv = gamma[c] * rsqrtf(var[c] + 1e-3f);
            bn[c] = inv;
            bn[64 + c] = beta[c] - mean[c] * inv;
        }
        return;
    }
    const int i = blockIdx.x * 256 + threadIdx.x;   // < 294912
    const int j  = i & 7;
    const int n  = (i >> 3) & 255;
    const int kg = (i >> 11) & 3;
    const int s  = i >> 13;            // 0..35
    const int sub = s % 18;
    const float* W = (s >= 18) ? Wh : Wx;
    const int k5 = sub * 32 + kg * 8 + j;
    const int c = k5 & 63, q = k5 >> 6;
    const int kx = q % 3, ky = q / 3;
    Wc[i] = f2h(W[(size_t)((ky * 3 + kx) * 64 + c) * 256 + n]);
}

// B-frag register loads: chunk ci, this lane's pair (nf=0 at boff, nf=1 at +128)
#define BLOAD(slot, ci) {                                                     \
    const unsigned short* _p = Wc + (size_t)(ci) * CHUNK + boff;              \
    bp[slot][0] = *(const half8*)_p;                                          \
    bp[slot][1] = *(const half8*)(_p + 128);                                  \
}

// 18-chunk conv pass (fallback fused kernel), B from reg pipeline.
template<int C0, int CLAST, int AOFF>
__device__ __forceinline__ void conv_pass18(
    const unsigned short* __restrict__ Wc, const int boff,
    half8 (&bp)[NB][2],
    const unsigned short* abase,
    f32x4 acc[2][2])
{
    #pragma unroll
    for (int sub = 0; sub < 18; ++sub) {
        const int ci = C0 + sub;
        if (ci + PF <= CLAST) BLOAD((ci + PF) % NB, ci + PF)

        const int ky = sub / 6, kx = (sub / 2) % 3, cb = sub & 1;
        const half8 b0 = bp[ci % NB][0];
        const half8 b1 = bp[ci % NB][1];
        const unsigned short* at = abase + AOFF + (ky * 34 + kx) * APAD + cb * 32;
        const half8 a0 = *(const half8*)(at);
        const half8 a1 = *(const half8*)(at + 16 * APAD);
        acc[0][0] = __builtin_amdgcn_mfma_f32_16x16x32_f16(a0, b0, acc[0][0], 0, 0, 0);
        acc[0][1] = __builtin_amdgcn_mfma_f32_16x16x32_f16(a0, b1, acc[0][1], 0, 0, 0);
        acc[1][0] = __builtin_amdgcn_mfma_f32_16x16x32_f16(a1, b0, acc[1][0], 0, 0, 0);
        acc[1][1] = __builtin_amdgcn_mfma_f32_16x16x32_f16(a1, b1, acc[1][1], 0, 0, 0);
    }
}

// Hoisted x-conv, 2 rows/block (unchanged geometry; staging stores now b128).
// record vi = ((((n*16+t)*64+y)*2+xh)*8+w)*64+lane -> 16 shorts [mfc][nf][j].
__global__ __launch_bounds__(512) void xconv_kernel(
    const float* __restrict__ x,
    const unsigned short* __restrict__ Wc,
    const float* __restrict__ bias,
    unsigned short* __restrict__ xg)
{
    const int bid0 = blockIdx.x;
    const int bid = (bid0 & 7) * 128 + (bid0 >> 3);  // bijective XCD swizzle
    const int y0 = (bid & 31) * 2;
    const int t  = (bid >> 5) & 15;
    const int n  = bid >> 9;
    const int tid = threadIdx.x, lane = tid & 63, w = tid >> 6;
    const int p0 = lane & 15, g = lane >> 4;

    __shared__ __align__(16) unsigned short smem[4 * 66 * APAD];

    const int boff = g * 2048 + (w * 32 + p0) * 8;

    half8 bp[NB][2];
    #pragma unroll
    for (int sc = 0; sc < PF; ++sc) BLOAD(sc, sc)

    // stage A tile rows y0-1..y0+2 (single b128 store per 16 channels)
    const float* __restrict__ xt = x + (size_t)(n * TT + t) * 4096 * 64;
    for (int idx = tid; idx < 4 * 66 * 8; idx += 512) {
        const int cg  = idx & 7;
        const int col = (idx >> 3) % 66;
        const int r   = (idx >> 3) / 66;
        const int gy = y0 + r - 1;
        const int gx = col - 1;
        const bool ok = ((unsigned)gy < 64u) && ((unsigned)gx < 64u);
        float4 v0 = make_float4(0.f, 0.f, 0.f, 0.f), v1 = v0;
        if (ok) {
            const float* p = xt + (size_t)(gy * 64 + gx) * 64 + cg * 8;
            v0 = *(const float4*)p;
            v1 = *(const float4*)(p + 4);
        }
        __align__(16) unsigned short os[8];
        os[0] = f2h(v0.x); os[1] = f2h(v0.y); os[2] = f2h(v0.z); os[3] = f2h(v0.w);
        os[4] = f2h(v1.x); os[5] = f2h(v1.y); os[6] = f2h(v1.z); os[7] = f2h(v1.w);
        *(uint4*)&smem[(r * 66 + col) * APAD + cg * 8] = *(const uint4*)os;
    }
    __syncthreads();

    const unsigned short* abase = smem + p0 * APAD + g * 8;

    f32x4 acc[8][2] = {};
    #pragma unroll
    for (int sub = 0; sub < 18; ++sub) {
        if (sub + PF < 18) BLOAD((sub + PF) % NB, sub + PF)

        const int ky = sub / 6, kx = (sub / 2) % 3, cb = sub & 1;
        const half8 b0 = bp[sub % NB][0];
        const half8 b1 = bp[sub % NB][1];
        #pragma unroll
        for (int mf = 0; mf < 8; ++mf) {
            const int r = mf >> 2, cq = mf & 3;
            const half8 a = *(const half8*)(abase
                + ((r + ky) * 66 + cq * 16 + kx) * APAD + cb * 32);
            acc[mf][0] = __builtin_amdgcn_mfma_f32_16x16x32_f16(a, b0, acc[mf][0], 0, 0, 0);
            acc[mf][1] = __builtin_amdgcn_mfma_f32_16x16x32_f16(a, b1, acc[mf][1], 0, 0, 0);
        }
    }

    const float bv0 = bias[w * 32 + p0];
    const float bv1 = bias[w * 32 + 16 + p0];
    #pragma unroll
    for (int r = 0; r < 2; ++r)
        #pragma unroll
        for (int xh2 = 0; xh2 < 2; ++xh2) {
            unsigned short os[16];
            #pragma unroll
            for (int mfc = 0; mfc < 2; ++mfc)
                #pragma unroll
                for (int nf = 0; nf < 2; ++nf)
                    #pragma unroll
                    for (int j = 0; j < 4; ++j)
                        os[mfc * 8 + nf * 4 + j] =
                            f2h(acc[r * 4 + xh2 * 2 + mfc][nf][j] + (nf ? bv1 : bv0));
            const size_t vi = ((((size_t)(n * TT + t) * 64 + (y0 + r)) * 2 + xh2) * 8 + w) * 64 + lane;
            unsigned short* dst = xg + vi * 16;
            *(uint4*)dst       = *(uint4*)&os[0];
            *(uint4*)(dst + 8) = *(uint4*)&os[8];
        }
}

// ---------------- Persistent recurrence kernel (all 16 steps, 1 dispatch) ----
// Block = (n,y,xhalf): 32 px x 256 ch, 8 waves, fixed pixel ownership all steps.
// Wh in registers (144 VGPR); c in 4 registers/thread; manual grid barrier.
__global__ __launch_bounds__(512) void lstm_persist(
    const unsigned short* __restrict__ xg,
    const unsigned short* __restrict__ Wc,
    unsigned short* __restrict__ hA,     // odd-t output buffer
    unsigned short* __restrict__ hB,     // even-t output buffer
    const float* __restrict__ bn,
    float* __restrict__ out,
    unsigned int* __restrict__ ctr)      // grid-barrier counter, zeroed by host
{
    const int bid0 = blockIdx.x;
    const int bid = (bid0 & 7) * 32 + (bid0 >> 3);   // bijective XCD swizzle
    const int xh = bid & 1;
    const int y  = (bid >> 1) & 63;
    const int n  = bid >> 7;
    const int tid = threadIdx.x;
    const int lane = tid & 63;
    const int w = tid >> 6;
    const int p0 = lane & 15;
    const int g  = lane >> 4;

    __shared__ __align__(16) unsigned short smem[17408];   // A-tile 14688B; gbuf 34816B

    // ---- load Wh slice into registers, once (chunks 18..35) ----
    const int boff = g * 2048 + (w * 32 + p0) * 8;
    half8 wr0[18], wr1[18];
    #pragma unroll
    for (int s = 0; s < 18; ++s) {
        const unsigned short* p = Wc + (size_t)(18 + s) * CHUNK + boff;
        wr0[s] = *(const half8*)p;
        wr1[s] = *(const half8*)(p + 128);
    }

    const unsigned short* abase = smem + p0 * APAD + g * 8;
    const size_t hbase = (size_t)n * 4096 * 64;
    float* gbuf = (float*)smem;                       // [4][32][68] f32

    // epilogue mapping (constant across steps)
    const int ep  = tid >> 4;
    const int ec4 = (tid & 15) * 4;
    const size_t esb = ((size_t)((n * 64 + y) * 64 + xh * 32 + ep)) * 64 + ec4;
    const float4 scv = *(const float4*)&bn[ec4];
    const float4 shv = *(const float4*)&bn[64 + ec4];
    float cr[4] = {0.f, 0.f, 0.f, 0.f};              // cell state in registers

    for (int t = 0; t < TT; ++t) {
        const unsigned short* hb = (t & 1) ? hB : hA;  // read buf (written at t-1)
        unsigned short*       ho = (t & 1) ? hA : hB;  // write buf

        // xg record for this step
        unsigned short xs[16];
        {
            const size_t vi = ((((size_t)(n * TT + t) * 64 + y) * 2 + xh) * 8 + w) * 64 + lane;
            const uint4* xp = (const uint4*)(xg + vi * 16);
            *(uint4*)&xs[0] = xp[0];
            *(uint4*)&xs[8] = xp[1];
        }

        f32x4 acc[2][2] = {};
        if (t > 0) {
            // stage h tile
            for (int idx = tid; idx < 3 * 34 * 8; idx += 512) {
                const int cg  = idx & 7;
                const int col = (idx >> 3) % 34;
                const int r   = (idx >> 3) / 34;
                const int gy = y + r - 1;
                const int gx = xh * 32 + col - 1;
                uint4 v = make_uint4(0u, 0u, 0u, 0u);
                if (((unsigned)gy < 64u) && ((unsigned)gx < 64u))
                    v = *(const uint4*)(hb + hbase + (size_t)(gy * 64 + gx) * 64 + cg * 8);
                *(uint4*)&smem[(r * 34 + col) * APAD + cg * 8] = v;
            }
            __syncthreads();

            // K-loop: B entirely from registers
            #pragma unroll
            for (int sub = 0; sub < 18; ++sub) {
                const int ky = sub / 6, kx = (sub / 2) % 3, cb = sub & 1;
                const unsigned short* at = abase + (ky * 34 + kx) * APAD + cb * 32;
                const half8 a0 = *(const half8*)(at);
                const half8 a1 = *(const half8*)(at + 16 * APAD);
                acc[0][0] = __builtin_amdgcn_mfma_f32_16x16x32_f16(a0, wr0[sub], acc[0][0], 0, 0, 0);
                acc[0][1] = __builtin_amdgcn_mfma_f32_16x16x32_f16(a0, wr1[sub], acc[0][1], 0, 0, 0);
                acc[1][0] = __builtin_amdgcn_mfma_f32_16x16x32_f16(a1, wr0[sub], acc[1][0], 0, 0, 0);
                acc[1][1] = __builtin_amdgcn_mfma_f32_16x16x32_f16(a1, wr1[sub], acc[1][1], 0, 0, 0);
            }
            __syncthreads();   // A-tile reads done; gbuf overlay safe
        }

        // gates -> gbuf (t=0: acc=0, z = xg only)
        const int gate = w >> 1;
        const int chalf = (w & 1) * 32;
        #pragma unroll
        for (int mf = 0; mf < 2; ++mf)
            #pragma unroll
            for (int nf = 0; nf < 2; ++nf)
                #pragma unroll
                for (int j = 0; j < 4; ++j) {
                    float v = acc[mf][nf][j] + h2f(xs[mf * 8 + nf * 4 + j]);
                    v = (gate == 2) ? tanhf(v) : hsig(v);   // gate order i,f,g,o
                    const int px = mf * 16 + g * 4 + j;
                    gbuf[(gate * 32 + px) * 68 + chalf + nf * 16 + p0] = v;
                }
        __syncthreads();

        // state update + BN output (c in registers)
        const float4 iv = *(const float4*)&gbuf[(0 * 32 + ep) * 68 + ec4];
        const float4 fv = *(const float4*)&gbuf[(1 * 32 + ep) * 68 + ec4];
        const float4 gv = *(const float4*)&gbuf[(2 * 32 + ep) * 68 + ec4];
        const float4 ov = *(const float4*)&gbuf[(3 * 32 + ep) * 68 + ec4];
        const float ivv[4] = {iv.x, iv.y, iv.z, iv.w};
        const float fvv[4] = {fv.x, fv.y, fv.z, fv.w};
        const float gvv[4] = {gv.x, gv.y, gv.z, gv.w};
        const float ovv[4] = {ov.x, ov.y, ov.z, ov.w};
        const float scc[4] = {scv.x, scv.y, scv.z, scv.w};
        const float shh[4] = {shv.x, shv.y, shv.z, shv.w};

        float obuf[4];
        us4 hh;
        unsigned short* hhp = (unsigned short*)&hh;
        #pragma unroll
        for (int j = 0; j < 4; ++j) {
            const float cn = fvv[j] * cr[j] + ivv[j] * gvv[j];
            const float hn = ovv[j] * tanhf(cn);
            cr[j] = cn;
            hhp[j] = f2h(hn);
            obuf[j] = hn * scc[j] + shh[j];
        }
        *(us4*)&ho[esb] = hh;
        const size_t ob = ((size_t)((n * TT + t) * 4096 + y * 64 + xh * 32 + ep)) * 64 + ec4;
        *(float4*)&out[ob] = *(float4*)&obuf[0];

        // grid barrier (monotonic counter; also protects gbuf/A-tile overlay)
        if (t < TT - 1) {
            __threadfence();
            __syncthreads();
            if (tid == 0) {
                __hip_atomic_fetch_add(ctr, 1u, __ATOMIC_ACQ_REL, __HIP_MEMORY_SCOPE_AGENT);
                const unsigned target = 256u * (unsigned)(t + 1);
                while (__hip_atomic_load(ctr, __ATOMIC_ACQUIRE, __HIP_MEMORY_SCOPE_AGENT) < target)
                    __builtin_amdgcn_s_sleep(2);
            }
            __syncthreads();
            __threadfence();
        }
    }
}

// Fallback fused per-step kernel (ws too small for xg): round-8/11 proven path.
__global__ __launch_bounds__(512) void convstep_fused(
    const float* __restrict__ x,
    const unsigned short* __restrict__ hb,
    const unsigned short* __restrict__ Wc,
    const float* __restrict__ bias,
    float* __restrict__ cbuf,
    unsigned short* __restrict__ ho,
    const float* __restrict__ bn,
    float* __restrict__ out,
    const int t)
{
    const int bid0 = blockIdx.x;
    const int bid = (bid0 & 7) * 32 + (bid0 >> 3);
    const int xh = bid & 1;
    const int y  = (bid >> 1) & 63;
    const int n  = bid >> 7;
    const int tid = threadIdx.x;
    const int lane = tid & 63;
    const int w = tid >> 6;
    const int p0 = lane & 15;
    const int g  = lane >> 4;

    __shared__ __align__(16) unsigned short smem[2 * A_TILE + 2720];  // >= gbuf 34816B

    const int boff = g * 2048 + (w * 32 + p0) * 8;
    half8 bp[NB][2];
    #pragma unroll
    for (int sc = 0; sc < PF; ++sc) BLOAD(sc, sc)

    const float* __restrict__ xt = x + (size_t)(n * TT + t) * 4096 * 64;
    const size_t hbase = (size_t)n * 4096 * 64;
    for (int idx = tid; idx < 2 * 3 * 34 * 8; idx += 512) {
        const int cg  = idx & 7;
        const int col = (idx >> 3) % 34;
        const int i3  = (idx >> 3) / 34;
        const int r   = i3 % 3;
        const int src = i3 / 3;
        const int gy = y + r - 1;
        const int gx = xh * 32 + col - 1;
        const bool ok = ((unsigned)gy < 64u) && ((unsigned)gx < 64u);
        const int ebase = (r * 34 + col) * APAD + cg * 8;
        if (src == 0) {
            float4 v0 = make_float4(0.f, 0.f, 0.f, 0.f), v1 = v0;
            if (ok) {
                const float* p = xt + (size_t)(gy * 64 + gx) * 64 + cg * 8;
                v0 = *(const float4*)p;
                v1 = *(const float4*)(p + 4);
            }
            __align__(16) unsigned short os[8];
            os[0] = f2h(v0.x); os[1] = f2h(v0.y); os[2] = f2h(v0.z); os[3] = f2h(v0.w);
            os[4] = f2h(v1.x); os[5] = f2h(v1.y); os[6] = f2h(v1.z); os[7] = f2h(v1.w);
            *(uint4*)&smem[ebase] = *(const uint4*)os;
        } else {
            uint4 v = make_uint4(0u, 0u, 0u, 0u);
            if (ok) v = *(const uint4*)(hb + hbase + (size_t)(gy * 64 + gx) * 64 + cg * 8);
            *(uint4*)&smem[A_TILE + ebase] = v;
        }
    }
    __syncthreads();

    const unsigned short* abase = smem + p0 * APAD + g * 8;
    f32x4 acc[2][2] = {};
    conv_pass18<0, 35, 0>(Wc, boff, bp, abase, acc);
    conv_pass18<18, 35, A_TILE>(Wc, boff, bp, abase, acc);

    __syncthreads();
    float* gbuf = (float*)smem;
    const int gate = w >> 1;
    const int chalf = (w & 1) * 32;
    float bv[2];
    bv[0] = bias[w * 32 + p0];
    bv[1] = bias[w * 32 + 16 + p0];

    #pragma unroll
    for (int mf = 0; mf < 2; ++mf)
        #pragma unroll
        for (int nf = 0; nf < 2; ++nf)
            #pragma unroll
            for (int j = 0; j < 4; ++j) {
                float v = acc[mf][nf][j] + bv[nf];
                v = (gate == 2) ? tanhf(v) : hsig(v);
                const int px = mf * 16 + g * 4 + j;
                gbuf[(gate * 32 + px) * 68 + chalf + nf * 16 + p0] = v;
            }
    __syncthreads();

    const int p  = tid >> 4;
    const int c4 = (tid & 15) * 4;
    const float4 iv = *(const float4*)&gbuf[(0 * 32 + p) * 68 + c4];
    const float4 fv = *(const float4*)&gbuf[(1 * 32 + p) * 68 + c4];
    const float4 gv = *(const float4*)&gbuf[(2 * 32 + p) * 68 + c4];
    const float4 ov = *(const float4*)&gbuf[(3 * 32 + p) * 68 + c4];
    const size_t sb = ((size_t)((n * 64 + y) * 64 + xh * 32 + p)) * 64 + c4;
    const float4 cold = *(const float4*)&cbuf[sb];
    const float4 scv  = *(const float4*)&bn[c4];
    const float4 shv  = *(const float4*)&bn[64 + c4];

    const float ivv[4] = {iv.x, iv.y, iv.z, iv.w};
    const float fvv[4] = {fv.x, fv.y, fv.z, fv.w};
    const float gvv[4] = {gv.x, gv.y, gv.z, gv.w};
    const float ovv[4] = {ov.x, ov.y, ov.z, ov.w};
    const float cov[4] = {cold.x, cold.y, cold.z, cold.w};
    const float scc[4] = {scv.x, scv.y, scv.z, scv.w};
    const float shh[4] = {shv.x, shv.y, shv.z, shv.w};

    float cnew[4], obuf[4];
    us4 hh;
    unsigned short* hhp = (unsigned short*)&hh;
    #pragma unroll
    for (int j = 0; j < 4; ++j) {
        const float cn = fvv[j] * cov[j] + ivv[j] * gvv[j];
        const float hn = ovv[j] * tanhf(cn);
        cnew[j] = cn;
        hhp[j] = f2h(hn);
        obuf[j] = hn * scc[j] + shh[j];
    }
    *(float4*)&cbuf[sb] = *(float4*)&cnew[0];
    *(us4*)&ho[sb]      = hh;
    const size_t ob = ((size_t)((n * TT + t) * 4096 + y * 64 + xh * 32 + p)) * 64 + c4;
    *(float4*)&out[ob] = *(float4*)&obuf[0];
}

extern "C" void kernel_launch(void* const* d_in, const int* in_sizes, int n_in,
                              void* d_out, int out_size, void* d_ws, size_t ws_size,
                              hipStream_t stream) {
    const float* x     = (const float*)d_in[0];
    const float* Wx    = (const float*)d_in[1];
    const float* Wh    = (const float*)d_in[2];
    const float* b     = (const float*)d_in[3];
    const float* gamma = (const float*)d_in[4];
    const float* beta  = (const float*)d_in[5];
    const float* mean  = (const float*)d_in[6];
    const float* var   = (const float*)d_in[7];
    float* out = (float*)d_out;
    char* ws = (char*)d_ws;

    unsigned short* Wc   = (unsigned short*)(ws);            // 589,824 B
    float*          bn   = (float*)(ws + 589824);            // 512 B
    unsigned short* hA   = (unsigned short*)(ws + 590336);   // 1 MB fp16
    unsigned int*   ctr  = (unsigned int*)(ws + 1638912);    // barrier counter
    float*          cbuf = (float*)(ws + 1638912);           // 2 MB (fallback only)
    unsigned short* hB   = (unsigned short*)(ws + 3736064);  // 1 MB fp16
    unsigned short* xg   = (unsigned short*)(ws + 4784640);  // 67,108,864 B
    const size_t NEED = 4784640ull + 67108864ull;            // 71,893,504 B

    prep_kernel<<<1153, 256, 0, stream>>>(Wx, Wh, gamma, beta, mean, var, Wc, bn);

    if (ws_size >= NEED) {
        hipMemsetAsync(ctr, 0, sizeof(unsigned int), stream);   // barrier counter = 0
        xconv_kernel<<<1024, 512, 0, stream>>>(x, Wc, b, xg);
        lstm_persist<<<256, 512, 0, stream>>>(xg, Wc, hA, hB, bn, out, ctr);
    } else {
        hipMemsetAsync(ws + 590336, 0, 3145728, stream);        // h0 + c0 = 0
        for (int t = 0; t < TT; ++t) {
            const bool even = (t & 1) == 0;
            convstep_fused<<<256, 512, 0, stream>>>(
                x, even ? hA : hB, Wc, b, cbuf, even ? hB : hA, bn, out, t);
        }
    }
}

// Round 13
// 200.773 us; speedup vs baseline: 7.1647x; 7.1647x over previous
//
#include <hip/hip_runtime.h>
#include <cstddef>

typedef __attribute__((ext_vector_type(8))) _Float16 half8;
typedef __attribute__((ext_vector_type(4))) float f32x4;
typedef __attribute__((ext_vector_type(4))) unsigned short us4;

#define TT 16
#define APAD 72                 // shorts per (row,col) slot: 144 B
#define A_TILE (3*34*APAD)      // step-kernel tile: 7344 shorts
#define CHUNK  8192             // shorts per 16KB weight chunk
#define NB     6                // B reg-pipeline slots (step kernel)
#define PF     5                // prefetch distance (< NB)
#define XNB    4                // B reg-pipeline slots (xconv)
#define XPF    3                // xconv prefetch distance (< XNB)

__device__ __forceinline__ unsigned short f2h(float f) {
    return __builtin_bit_cast(unsigned short, (_Float16)f);
}
__device__ __forceinline__ float h2f(unsigned short u) {
    return (float)__builtin_bit_cast(_Float16, u);
}
__device__ __forceinline__ float hsig(float z) {
    return fminf(fmaxf(0.2f * z + 0.5f, 0.f), 1.f);
}

// Weight pack (fp16): Wc short idx i = (s*4 + kg)*2048 + n*8 + j, s in [0,36)
// s<18 -> Wx chunk sub=s ; s>=18 -> Wh chunk sub=s-18
__global__ __launch_bounds__(256) void prep_kernel(
    const float* __restrict__ Wx, const float* __restrict__ Wh,
    const float* __restrict__ gamma, const float* __restrict__ beta,
    const float* __restrict__ mean, const float* __restrict__ var,
    unsigned short* __restrict__ Wc, float* __restrict__ bn)
{
    if (blockIdx.x == 1152) {
        if (threadIdx.x < 64) {
            const int c = threadIdx.x;
            const float inv = gamma[c] * rsqrtf(var[c] + 1e-3f);
            bn[c] = inv;
            bn[64 + c] = beta[c] - mean[c] * inv;
        }
        return;
    }
    const int i = blockIdx.x * 256 + threadIdx.x;   // < 294912
    const int j  = i & 7;
    const int n  = (i >> 3) & 255;
    const int kg = (i >> 11) & 3;
    const int s  = i >> 13;            // 0..35
    const int sub = s % 18;
    const float* W = (s >= 18) ? Wh : Wx;
    const int k5 = sub * 32 + kg * 8 + j;
    const int c = k5 & 63, q = k5 >> 6;
    const int kx = q % 3, ky = q / 3;
    Wc[i] = f2h(W[(size_t)((ky * 3 + kx) * 64 + c) * 256 + n]);
}

// B-frag register loads: chunk ci, this lane's pair (nf=0 at boff, nf=1 at +128)
#define BLOAD(slot, ci) {                                                     \
    const unsigned short* _p = Wc + (size_t)(ci) * CHUNK + boff;              \
    bp[slot][0] = *(const half8*)_p;                                          \
    bp[slot][1] = *(const half8*)(_p + 128);                                  \
}

// 18-chunk conv pass (step kernel), B from reg pipeline.
template<int C0, int CLAST, int AOFF>
__device__ __forceinline__ void conv_pass18(
    const unsigned short* __restrict__ Wc, const int boff,
    half8 (&bp)[NB][2],
    const unsigned short* abase,
    f32x4 acc[2][2])
{
    #pragma unroll
    for (int sub = 0; sub < 18; ++sub) {
        const int ci = C0 + sub;
        if (ci + PF <= CLAST) BLOAD((ci + PF) % NB, ci + PF)

        const int ky = sub / 6, kx = (sub / 2) % 3, cb = sub & 1;
        const half8 b0 = bp[ci % NB][0];
        const half8 b1 = bp[ci % NB][1];
        const unsigned short* at = abase + AOFF + (ky * 34 + kx) * APAD + cb * 32;
        const half8 a0 = *(const half8*)(at);
        const half8 a1 = *(const half8*)(at + 16 * APAD);
        acc[0][0] = __builtin_amdgcn_mfma_f32_16x16x32_f16(a0, b0, acc[0][0], 0, 0, 0);
        acc[0][1] = __builtin_amdgcn_mfma_f32_16x16x32_f16(a0, b1, acc[0][1], 0, 0, 0);
        acc[1][0] = __builtin_amdgcn_mfma_f32_16x16x32_f16(a1, b0, acc[1][0], 0, 0, 0);
        acc[1][1] = __builtin_amdgcn_mfma_f32_16x16x32_f16(a1, b1, acc[1][1], 0, 0, 0);
    }
}

// Hoisted x-conv, 1 row/block (occupancy: ~84 VGPR + 28.5KB LDS -> 3 blocks/CU).
// record vi = ((((n*16+t)*64+y)*2+xh)*8+w)*64+lane -> 16 shorts [mfc][nf][j].
__global__ __launch_bounds__(512) void xconv_kernel(
    const float* __restrict__ x,
    const unsigned short* __restrict__ Wc,
    const float* __restrict__ bias,
    unsigned short* __restrict__ xg)
{
    const int bid0 = blockIdx.x;
    const int bid = (bid0 & 7) * 256 + (bid0 >> 3);  // bijective XCD swizzle (2048=8*256)
    const int y = bid & 63;
    const int t = (bid >> 6) & 15;
    const int n = bid >> 10;
    const int tid = threadIdx.x, lane = tid & 63, w = tid >> 6;
    const int p0 = lane & 15, g = lane >> 4;

    // A tile: [3 rows][66 cols][APAD] fp16 = 28512 B
    __shared__ __align__(16) unsigned short smem[3 * 66 * APAD];

    const int boff = g * 2048 + (w * 32 + p0) * 8;

    half8 bp[XNB][2];
    #pragma unroll
    for (int sc = 0; sc < XPF; ++sc) BLOAD(sc, sc)

    // stage A tile rows y-1..y+1
    const float* __restrict__ xt = x + (size_t)(n * TT + t) * 4096 * 64;
    for (int idx = tid; idx < 3 * 66 * 8; idx += 512) {
        const int cg  = idx & 7;
        const int col = (idx >> 3) % 66;
        const int r   = (idx >> 3) / 66;
        const int gy = y + r - 1;
        const int gx = col - 1;
        const bool ok = ((unsigned)gy < 64u) && ((unsigned)gx < 64u);
        float4 v0 = make_float4(0.f, 0.f, 0.f, 0.f), v1 = v0;
        if (ok) {
            const float* p = xt + (size_t)(gy * 64 + gx) * 64 + cg * 8;
            v0 = *(const float4*)p;
            v1 = *(const float4*)(p + 4);
        }
        __align__(16) unsigned short os[8];
        os[0] = f2h(v0.x); os[1] = f2h(v0.y); os[2] = f2h(v0.z); os[3] = f2h(v0.w);
        os[4] = f2h(v1.x); os[5] = f2h(v1.y); os[6] = f2h(v1.z); os[7] = f2h(v1.w);
        *(uint4*)&smem[(r * 66 + col) * APAD + cg * 8] = *(const uint4*)os;
    }
    __syncthreads();

    const unsigned short* abase = smem + p0 * APAD + g * 8;

    // K-loop: 18 chunks (Wx), 4 m-frags (64 px), B from regs
    f32x4 acc[4][2] = {};
    #pragma unroll
    for (int sub = 0; sub < 18; ++sub) {
        if (sub + XPF < 18) BLOAD((sub + XPF) % XNB, sub + XPF)

        const int ky = sub / 6, kx = (sub / 2) % 3, cb = sub & 1;
        const half8 b0 = bp[sub % XNB][0];
        const half8 b1 = bp[sub % XNB][1];
        #pragma unroll
        for (int cq = 0; cq < 4; ++cq) {
            const half8 a = *(const half8*)(abase
                + (ky * 66 + cq * 16 + kx) * APAD + cb * 32);
            acc[cq][0] = __builtin_amdgcn_mfma_f32_16x16x32_f16(a, b0, acc[cq][0], 0, 0, 0);
            acc[cq][1] = __builtin_amdgcn_mfma_f32_16x16x32_f16(a, b1, acc[cq][1], 0, 0, 0);
        }
    }

    // packed xg store: 2 records (xh) of 32 B per lane; cq = xh*2 + mfc
    const float bv0 = bias[w * 32 + p0];
    const float bv1 = bias[w * 32 + 16 + p0];
    #pragma unroll
    for (int xh2 = 0; xh2 < 2; ++xh2) {
        unsigned short os[16];
        #pragma unroll
        for (int mfc = 0; mfc < 2; ++mfc)
            #pragma unroll
            for (int nf = 0; nf < 2; ++nf)
                #pragma unroll
                for (int j = 0; j < 4; ++j)
                    os[mfc * 8 + nf * 4 + j] =
                        f2h(acc[xh2 * 2 + mfc][nf][j] + (nf ? bv1 : bv0));
        const size_t vi = ((((size_t)(n * TT + t) * 64 + y) * 2 + xh2) * 8 + w) * 64 + lane;
        unsigned short* dst = xg + vi * 16;
        *(uint4*)dst       = *(uint4*)&os[0];
        *(uint4*)(dst + 8) = *(uint4*)&os[8];
    }
}

// Per-timestep kernel. FUSED=1: full x+h conv (ws fallback). FUSED=0: h-conv + xg.
// Block = (n,y,xhalf): 32 px x 256 ch, 8 waves.
template<int FUSED>
__global__ __launch_bounds__(512) void convstep_kernel(
    const float* __restrict__ x,
    const unsigned short* __restrict__ hb,
    const unsigned short* __restrict__ Wc,
    const float* __restrict__ bias,
    const unsigned short* __restrict__ xg,
    float* __restrict__ cbuf,
    unsigned short* __restrict__ ho,
    const float* __restrict__ bn,
    float* __restrict__ out,
    const int t)
{
    const int bid0 = blockIdx.x;
    const int bid = (bid0 & 7) * 32 + (bid0 >> 3);   // bijective XCD swizzle
    const int xh = bid & 1;
    const int y  = (bid >> 1) & 63;
    const int n  = bid >> 7;
    const int tid = threadIdx.x;
    const int lane = tid & 63;
    const int w = tid >> 6;
    const int p0 = lane & 15;
    const int g  = lane >> 4;

    // smem: A tiles; overlaid by gate buffer [4][32][68] f32 = 34816 B after K-loop
    constexpr int SMEM_SHORTS = FUSED ? (2 * A_TILE) : 17408;   // FUSED0: 34816 B
    __shared__ __align__(16) unsigned short smem[SMEM_SHORTS];

    const int boff = g * 2048 + (w * 32 + p0) * 8;

    // packed xg prefetch: one 32B record per lane
    unsigned short xs[16];
    if (!FUSED) {
        const size_t vi = ((((size_t)(n * TT + t) * 64 + y) * 2 + xh) * 8 + w) * 64 + lane;
        const uint4* xp = (const uint4*)(xg + vi * 16);
        *(uint4*)&xs[0] = xp[0];
        *(uint4*)&xs[8] = xp[1];
    }

    // B prologue into regs (latency hides under A-staging)
    constexpr int C0 = FUSED ? 0 : 18;
    half8 bp[NB][2];
    #pragma unroll
    for (int sc = 0; sc < PF; ++sc) BLOAD((C0 + sc) % NB, C0 + sc)

    // ---- stage A tiles: FUSED: x(tile0) + h(tile1); else h(tile0) ----
    constexpr int NTILE = FUSED ? 2 : 1;
    const float* __restrict__ xt = x + (size_t)(n * TT + t) * 4096 * 64;
    const size_t hbase = (size_t)n * 4096 * 64;
    for (int idx = tid; idx < NTILE * 3 * 34 * 8; idx += 512) {
        const int cg  = idx & 7;
        const int col = (idx >> 3) % 34;
        const int i3  = (idx >> 3) / 34;
        const int r   = i3 % 3;
        const int src = i3 / 3;
        const int gy = y + r - 1;
        const int gx = xh * 32 + col - 1;
        const bool ok = ((unsigned)gy < 64u) && ((unsigned)gx < 64u);
        const int ebase = (r * 34 + col) * APAD + cg * 8;
        if (FUSED && src == 0) {
            float4 v0 = make_float4(0.f, 0.f, 0.f, 0.f), v1 = v0;
            if (ok) {
                const float* p = xt + (size_t)(gy * 64 + gx) * 64 + cg * 8;
                v0 = *(const float4*)p;
                v1 = *(const float4*)(p + 4);
            }
            __align__(16) unsigned short os[8];
            os[0] = f2h(v0.x); os[1] = f2h(v0.y); os[2] = f2h(v0.z); os[3] = f2h(v0.w);
            os[4] = f2h(v1.x); os[5] = f2h(v1.y); os[6] = f2h(v1.z); os[7] = f2h(v1.w);
            *(uint4*)&smem[ebase] = *(const uint4*)os;
        } else {
            uint4 v = make_uint4(0u, 0u, 0u, 0u);
            if (ok) v = *(const uint4*)(hb + hbase + (size_t)(gy * 64 + gx) * 64 + cg * 8);
            *(uint4*)&smem[(FUSED ? A_TILE : 0) + ebase] = v;
        }
    }
    __syncthreads();

    // ---- K-loop (B from reg pipeline, compiler-managed waits) ----
    const unsigned short* abase = smem + p0 * APAD + g * 8;

    f32x4 acc[2][2] = {};
    if (FUSED) {
        conv_pass18<0, 35, 0>(Wc, boff, bp, abase, acc);
        conv_pass18<18, 35, A_TILE>(Wc, boff, bp, abase, acc);
    } else {
        conv_pass18<18, 35, 0>(Wc, boff, bp, abase, acc);
    }

    // ---- gates -> LDS gate buffer (overlay A region) ----
    __syncthreads();
    float* gbuf = (float*)smem;            // [4][32][68] f32 = 34816 B
    const int gate = w >> 1;
    const int chalf = (w & 1) * 32;

    float bv[2];
    bv[0] = bias[w * 32 + p0];
    bv[1] = bias[w * 32 + 16 + p0];

    #pragma unroll
    for (int mf = 0; mf < 2; ++mf)
        #pragma unroll
        for (int nf = 0; nf < 2; ++nf)
            #pragma unroll
            for (int j = 0; j < 4; ++j) {
                float v = acc[mf][nf][j] + (FUSED ? bv[nf] : h2f(xs[mf * 8 + nf * 4 + j]));
                v = (gate == 2) ? tanhf(v) : hsig(v);   // gate order i,f,g,o
                const int px = mf * 16 + g * 4 + j;
                gbuf[(gate * 32 + px) * 68 + chalf + nf * 16 + p0] = v;
            }
    __syncthreads();

    // ---- state update + BN output ----
    const int p  = tid >> 4;
    const int c4 = (tid & 15) * 4;
    const float4 iv = *(const float4*)&gbuf[(0 * 32 + p) * 68 + c4];
    const float4 fv = *(const float4*)&gbuf[(1 * 32 + p) * 68 + c4];
    const float4 gv = *(const float4*)&gbuf[(2 * 32 + p) * 68 + c4];
    const float4 ov = *(const float4*)&gbuf[(3 * 32 + p) * 68 + c4];
    const size_t gpix = (size_t)((n * 64 + y) * 64 + xh * 32 + p);
    const size_t sb = gpix * 64 + c4;
    const float4 cold = *(const float4*)&cbuf[sb];
    const float4 scv  = *(const float4*)&bn[c4];
    const float4 shv  = *(const float4*)&bn[64 + c4];

    const float ivv[4] = {iv.x, iv.y, iv.z, iv.w};
    const float fvv[4] = {fv.x, fv.y, fv.z, fv.w};
    const float gvv[4] = {gv.x, gv.y, gv.z, gv.w};
    const float ovv[4] = {ov.x, ov.y, ov.z, ov.w};
    const float cov[4] = {cold.x, cold.y, cold.z, cold.w};
    const float scc[4] = {scv.x, scv.y, scv.z, scv.w};
    const float shh[4] = {shv.x, shv.y, shv.z, shv.w};

    float cnew[4], obuf[4];
    us4 hh;
    unsigned short* hhp = (unsigned short*)&hh;
    #pragma unroll
    for (int j = 0; j < 4; ++j) {
        const float cn = fvv[j] * cov[j] + ivv[j] * gvv[j];
        const float hn = ovv[j] * tanhf(cn);
        cnew[j] = cn;
        hhp[j] = f2h(hn);
        obuf[j] = hn * scc[j] + shh[j];
    }
    *(float4*)&cbuf[sb] = *(float4*)&cnew[0];
    *(us4*)&ho[sb]      = hh;
    const size_t ob = ((size_t)((n * TT + t) * 4096 + y * 64 + xh * 32 + p)) * 64 + c4;
    *(float4*)&out[ob] = *(float4*)&obuf[0];
}

extern "C" void kernel_launch(void* const* d_in, const int* in_sizes, int n_in,
                              void* d_out, int out_size, void* d_ws, size_t ws_size,
                              hipStream_t stream) {
    const float* x     = (const float*)d_in[0];
    const float* Wx    = (const float*)d_in[1];
    const float* Wh    = (const float*)d_in[2];
    const float* b     = (const float*)d_in[3];
    const float* gamma = (const float*)d_in[4];
    const float* beta  = (const float*)d_in[5];
    const float* mean  = (const float*)d_in[6];
    const float* var   = (const float*)d_in[7];
    float* out = (float*)d_out;
    char* ws = (char*)d_ws;

    unsigned short* Wc   = (unsigned short*)(ws);            // 589,824 B
    float*          bn   = (float*)(ws + 589824);            // 512 B
    unsigned short* hA   = (unsigned short*)(ws + 590336);   // 1 MB fp16
    float*          cbuf = (float*)(ws + 1638912);           // 2 MB fp32
    unsigned short* hB   = (unsigned short*)(ws + 3736064);  // 1 MB fp16
    unsigned short* xg   = (unsigned short*)(ws + 4784640);  // 67,108,864 B
    const size_t NEED = 4784640ull + 67108864ull;            // 71,893,504 B

    hipMemsetAsync(ws + 590336, 0, 3145728, stream);         // h0 + c0 = 0
    prep_kernel<<<1153, 256, 0, stream>>>(Wx, Wh, gamma, beta, mean, var, Wc, bn);

    if (ws_size >= NEED) {
        xconv_kernel<<<2048, 512, 0, stream>>>(x, Wc, b, xg);
        for (int t = 0; t < TT; ++t) {
            const bool even = (t & 1) == 0;
            convstep_kernel<0><<<256, 512, 0, stream>>>(
                x, even ? hA : hB, Wc, b, xg, cbuf, even ? hB : hA, bn, out, t);
        }
    } else {
        for (int t = 0; t < TT; ++t) {
            const bool even = (t & 1) == 0;
            convstep_kernel<1><<<256, 512, 0, stream>>>(
                x, even ? hA : hB, Wc, b, xg, cbuf, even ? hB : hA, bn, out, t);
        }
    }
}